// Round 16
// baseline (108.105 us; speedup 1.0000x reference)
//
#include <hip/hip_runtime.h>
#include <hip/hip_bf16.h>

// ---- problem constants (match reference) ----
#define HIN   721
#define WIN   1440
#define HOUT_ 361
#define WOUT_ 720
#define NB    4
#define CIN_  8
#define COUT_ 32
#define KT    9
#define NNZ_  32
// derived: PSCALE = 2, base_row(x) = 2x exactly, cols in [0,16)
// q = c*10 + 2s + e  (80 values), j = col>>1 (8 values)

typedef short  bsh8   __attribute__((ext_vector_type(8)));   // 8 bf16 (4 VGPR) MFMA frag
typedef float  f32x16 __attribute__((ext_vector_type(16)));  // 32x32 MFMA acc
typedef unsigned int u32x4 __attribute__((ext_vector_type(4)));

static __device__ __forceinline__ unsigned short f2bf(float f) {
  unsigned u = __builtin_bit_cast(unsigned, f);
  u += 0x7fffu + ((u >> 16) & 1u);      // RNE
  return (unsigned short)(u >> 16);
}

static __device__ __forceinline__ unsigned pack2(float a, float b) {
  __hip_bfloat162 h = __float22bfloat162_rn(make_float2(a, b));
  unsigned u; __builtin_memcpy(&u, &h, 4);
  return u;                              // a -> low 16, b -> high 16
}

// =====================================================================
// K1: build combined coefficients — slim-LDS (45.4KB -> 3 blocks/CU,
// all 361 blocks co-resident; R12 verified −6us).
// =====================================================================
__global__ __launch_bounds__(256, 3) void coeff_kernel(
    const int*   __restrict__ psi_idx,
    const float* __restrict__ psi_vals,
    const float* __restrict__ weight,
    unsigned short* __restrict__ Cg)
{
  __shared__ unsigned short Cl16[256 * 83];   // 42496 B
  __shared__ float S[KT][80];                 // 2880 B

  const int x = blockIdx.x, tid = threadIdx.x;

  for (int i = tid; i < KT * 80; i += 256) ((float*)S)[i] = 0.f;
  __syncthreads();

  for (int i = tid; i < KT * NNZ_; i += 256) {   // scatter all 288 taps
    int k = i >> 5, n = i & 31;
    int gi  = (k * HOUT_ + x) * NNZ_ + n;
    int idx = psi_idx[gi];
    int r   = idx / WIN;
    int col = idx - r * WIN;               // in [0,16)
    int s   = r - 2 * x + 2;               // in [0,4] after reference clip
    int slot = (s * 2 + (col & 1)) * 8 + (col >> 1);
    atomicAdd(&S[k][slot], psi_vals[gi]);
  }

  // thread (o = tid>>3, c = tid&7) reads its own 9 weights from global
  float w[KT];
  #pragma unroll
  for (int k = 0; k < KT; ++k) w[k] = weight[tid * KT + k];
  __syncthreads();

  { // dense combine, bf16 write
    unsigned short* seg = &Cl16[tid * 83];
    #pragma unroll
    for (int slot = 0; slot < 80; ++slot) {
      float acc = 0.f;
      #pragma unroll
      for (int k = 0; k < KT; ++k) acc += w[k] * S[k][slot];
      seg[slot] = f2bf(acc);
    }
  }
  __syncthreads();

  // writeback as 16B chunks: Cg[((x*8+j)*10+qb)*32+o][qi0..7]
  for (int chunk = tid; chunk < 8 * 10 * 32; chunk += 256) {
    int j   = chunk / 320;
    int rem = chunk - j * 320;
    int qb  = rem >> 5, o = rem & 31;
    u32x4 pack;
    #pragma unroll
    for (int h = 0; h < 4; ++h) {
      int q0 = qb * 8 + 2 * h;
      int c0 = q0 / 10, ql0 = q0 - c0 * 10;
      int q1 = q0 + 1;
      int c1 = q1 / 10, ql1 = q1 - c1 * 10;
      unsigned lo = Cl16[(o * CIN_ + c0) * 83 + ql0 * 8 + j];
      unsigned hi = Cl16[(o * CIN_ + c1) * 83 + ql1 * 8 + j];
      pack[h] = lo | (hi << 16);
    }
    *(u32x4*)&Cg[((size_t)x * 2560 + (size_t)((j * 10 + qb) * 32 + o)) * 8] = pack;
  }
}

// =====================================================================
// K2: main compute — R13/R15 configuration (best measured, reproduced
// twice: 86.26 / 86.35 us graph). Only change this round: plain stores
// instead of nontemporal (isolated A/B — nt bypasses L2; regular stores
// let L2/L3 absorb the 132MB write burst).
//  - PB=256, 2 acc/wave; RST=176 no-swizzle (48 mod 128 walk -> b128
//    reads at the 8-dword/bank floor); rowpair b128 writes ~2-way.
//  - A-frag 2-slot rotation afr[j&1]; j=0/1 issued before staging.
//  - B-frag depth-1 cross-j prefetch; s_setprio(1) around MFMA cluster.
//  - LDS 264*176 = 46464B -> 3 blocks/CU.
// Plateau note: occupancy-invariance (R4/R6/R7 equal throughput at
// 24/16/12 waves) + 5 negative structural mutations (R9/R10/R11/R14,
// fused coeff) place this decomposition at its plain-HIP latency
// plateau, ~2.3x the 37us pure-HBM floor.
// =====================================================================
#define PB   256
#define ROWS 264            // max row read = 262
#define RST  176            // 176 mod 128 = 48 -> b128 reads at bank floor

__global__ __launch_bounds__(256, 3) void disco_main_kernel(
    const float* __restrict__ x,
    const unsigned short* __restrict__ Cg,
    float* __restrict__ out)
{
  __shared__ __align__(16) unsigned char Ut[ROWS * RST];  // 46464 B

  // ---- bijective XCD-chunked decode (nwg = 4332 = 8*541 + 4, m204) ----
  const int g   = blockIdx.x;
  const int xcd = g & 7, lin = g >> 3;
  const int swz = (xcd < 4) ? xcd * 542 + lin : 4 * 542 + (xcd - 4) * 541 + lin;
  const int xo  = swz / 12;
  const int rem = swz - xo * 12;
  const int pt  = rem % 3;          // 0..2
  const int b   = rem / 3;          // 0..3
  const int p0  = pt * PB;
  const int tid = threadIdx.x;

  const int lane = tid & 63;
  const int wv   = tid >> 6;        // 0..3: 64-wide p slice
  const int half = lane >> 5;       // k-slice half (chunk parity)
  const int l31  = lane & 31;
  const int wbase = wv * 64;

  const unsigned short* cgx = Cg + (size_t)xo * 2560 * 8
                                 + (size_t)(half * 32 + l31) * 8;

  // ---- A-frags for j=0 and j=1 issued first: overlap staging + barrier ----
  bsh8 afr[2][5];
  #pragma unroll
  for (int kb = 0; kb < 5; ++kb) afr[0][kb] = *(const bsh8*)&cgx[kb * 512];
  #pragma unroll
  for (int kb = 0; kb < 5; ++kb) afr[1][kb] = *(const bsh8*)&cgx[2560 + kb * 512];

  const float* xb = x + (size_t)b * (CIN_ * HIN * WIN);

  int rr[5];
  #pragma unroll
  for (int s = 0; s < 5; ++s) {
    int r = 2 * xo + s - 2;
    rr[s] = r < 0 ? 0 : (r > HIN - 1 ? HIN - 1 : r);
  }

  // ---- stage Ut: 1320 units (ch = u/132, rp = u%132 -> rows 2rp,2rp+1) ----
  // unit: 4 float4 loads (q-pairs 4ch+m, m=0..3) -> 2x ds_write_b128
  #pragma unroll
  for (int bp = 0; bp < 2; ++bp) {
    float4 v0[4], v1[4];
    const int uA = tid + (2 * bp) * 256, uB = uA + 256;
    const int chA = uA / 132, rpA = uA - chA * 132;
    const int chB = uB / 132, rpB = uB - chB * 132;
    int cwA = p0 + 2 * rpA; if (cwA >= WOUT_) cwA -= WOUT_;
    int cwB = p0 + 2 * rpB; if (cwB >= WOUT_) cwB -= WOUT_;
    #pragma unroll
    for (int m = 0; m < 4; ++m) {
      int qpA = 4 * chA + m, cA = (qpA * 205) >> 10, sA = qpA - cA * 5;
      v0[m] = *(const float4*)&xb[(size_t)(cA * HIN + rr[sA]) * WIN + 2 * cwA];
      int qpB = 4 * chB + m, cB = (qpB * 205) >> 10, sB = qpB - cB * 5;
      v1[m] = *(const float4*)&xb[(size_t)(cB * HIN + rr[sB]) * WIN + 2 * cwB];
    }
    u32x4 lo, hi;
    #pragma unroll
    for (int m = 0; m < 4; ++m) { lo[m] = pack2(v0[m].x, v0[m].y); hi[m] = pack2(v0[m].z, v0[m].w); }
    int byte0 = (2 * rpA) * RST + chA * 16;
    *(u32x4*)&Ut[byte0]       = lo;
    *(u32x4*)&Ut[byte0 + RST] = hi;
    #pragma unroll
    for (int m = 0; m < 4; ++m) { lo[m] = pack2(v1[m].x, v1[m].y); hi[m] = pack2(v1[m].z, v1[m].w); }
    byte0 = (2 * rpB) * RST + chB * 16;
    *(u32x4*)&Ut[byte0]       = lo;
    *(u32x4*)&Ut[byte0 + RST] = hi;
  }
  { // unit pass 5 (u in [1024,1280)) + tail (u in [1280,1320), tid < 40)
    const int uA = tid + 1024;
    const int chA = uA / 132, rpA = uA - chA * 132;
    int cwA = p0 + 2 * rpA; if (cwA >= WOUT_) cwA -= WOUT_;
    float4 v0[4], v1[4];
    int chB = 0, rpB = 0;
    const bool tail = tid < 40;
    if (tail) {
      const int uB = tid + 1280;
      chB = uB / 132; rpB = uB - chB * 132;
    }
    int cwB = p0 + 2 * rpB; if (cwB >= WOUT_) cwB -= WOUT_;
    #pragma unroll
    for (int m = 0; m < 4; ++m) {
      int qpA = 4 * chA + m, cA = (qpA * 205) >> 10, sA = qpA - cA * 5;
      v0[m] = *(const float4*)&xb[(size_t)(cA * HIN + rr[sA]) * WIN + 2 * cwA];
    }
    if (tail) {
      #pragma unroll
      for (int m = 0; m < 4; ++m) {
        int qpB = 4 * chB + m, cB = (qpB * 205) >> 10, sB = qpB - cB * 5;
        v1[m] = *(const float4*)&xb[(size_t)(cB * HIN + rr[sB]) * WIN + 2 * cwB];
      }
    }
    u32x4 lo, hi;
    #pragma unroll
    for (int m = 0; m < 4; ++m) { lo[m] = pack2(v0[m].x, v0[m].y); hi[m] = pack2(v0[m].z, v0[m].w); }
    int byte0 = (2 * rpA) * RST + chA * 16;
    *(u32x4*)&Ut[byte0]       = lo;
    *(u32x4*)&Ut[byte0 + RST] = hi;
    if (tail) {
      #pragma unroll
      for (int m = 0; m < 4; ++m) { lo[m] = pack2(v1[m].x, v1[m].y); hi[m] = pack2(v1[m].z, v1[m].w); }
      byte0 = (2 * rpB) * RST + chB * 16;
      *(u32x4*)&Ut[byte0]       = lo;
      *(u32x4*)&Ut[byte0 + RST] = hi;
    }
  }
  __syncthreads();

  // ---- MFMA phase: cross-j pipelined ----
  f32x16 acc0 = {};
  f32x16 acc1 = {};

  bsh8 bc0[5], bc1[5];                 // current-j B-frags
  {
    const int rb0 = (wbase + l31) * RST;
    const int rb1 = rb0 + 32 * RST;
    #pragma unroll
    for (int kb = 0; kb < 5; ++kb) {
      const int cho = (2 * kb + half) * 16;
      bc0[kb] = *(const bsh8*)&Ut[rb0 + cho];
      bc1[kb] = *(const bsh8*)&Ut[rb1 + cho];
    }
  }

  #pragma unroll
  for (int j = 0; j < 8; ++j) {
    bsh8 bn0[5], bn1[5];
    if (j < 7) {                       // prefetch j+1's B-frags first
      const int rb0 = (wbase + l31 + j + 1) * RST;
      const int rb1 = rb0 + 32 * RST;
      #pragma unroll
      for (int kb = 0; kb < 5; ++kb) {
        const int cho = (2 * kb + half) * 16;
        bn0[kb] = *(const bsh8*)&Ut[rb0 + cho];
        bn1[kb] = *(const bsh8*)&Ut[rb1 + cho];
      }
    }
    __builtin_amdgcn_s_setprio(1);
    #pragma unroll
    for (int kb = 0; kb < 5; ++kb) {
      acc0 = __builtin_amdgcn_mfma_f32_32x32x16_bf16(afr[j & 1][kb], bc0[kb], acc0, 0, 0, 0);
      acc1 = __builtin_amdgcn_mfma_f32_32x32x16_bf16(afr[j & 1][kb], bc1[kb], acc1, 0, 0, 0);
    }
    __builtin_amdgcn_s_setprio(0);
    if (j < 6) {                       // reload this slot with j+2's A-frags
      #pragma unroll
      for (int kb = 0; kb < 5; ++kb)
        afr[j & 1][kb] = *(const bsh8*)&cgx[(j + 2) * 2560 + kb * 512];
    }
    #pragma unroll
    for (int kb = 0; kb < 5; ++kb) { bc0[kb] = bn0[kb]; bc1[kb] = bn1[kb]; }
  }

  // ---- store: D col = l31 -> p, row o = (r&3) + 8*(r>>2) + 4*half ----
  // plain stores (A/B vs nontemporal): let L2/L3 absorb the write burst
  const int p = p0 + wbase + l31;
  #pragma unroll
  for (int r = 0; r < 16; ++r) {
    int o = (r & 3) + 8 * (r >> 2) + 4 * half;
    size_t base = ((size_t)(b * COUT_ + o) * HOUT_ + xo) * WOUT_;
    if (p < WOUT_)      out[base + p]      = acc0[r];
    if (p + 32 < WOUT_) out[base + p + 32] = acc1[r];
  }
}

extern "C" void kernel_launch(void* const* d_in, const int* in_sizes, int n_in,
                              void* d_out, int out_size, void* d_ws, size_t ws_size,
                              hipStream_t stream) {
  const float* x        = (const float*)d_in[0];
  const int*   psi_idx  = (const int*)d_in[1];
  const float* psi_vals = (const float*)d_in[2];
  const float* weight   = (const float*)d_in[3];
  float* out = (float*)d_out;
  unsigned short* Cg = (unsigned short*)d_ws;   // 361*2560*8 bf16 = 14.8 MB

  coeff_kernel<<<dim3(HOUT_), 256, 0, stream>>>(psi_idx, psi_vals, weight, Cg);
  disco_main_kernel<<<dim3(3 * NB * HOUT_), 256, 0, stream>>>(x, Cg, out);
}

// Round 17
// 86.243 us; speedup vs baseline: 1.2535x; 1.2535x over previous
//
#include <hip/hip_runtime.h>
#include <hip/hip_bf16.h>

// ---- problem constants (match reference) ----
#define HIN   721
#define WIN   1440
#define HOUT_ 361
#define WOUT_ 720
#define NB    4
#define CIN_  8
#define COUT_ 32
#define KT    9
#define NNZ_  32
// derived: PSCALE = 2, base_row(x) = 2x exactly, cols in [0,16)
// q = c*10 + 2s + e  (80 values), j = col>>1 (8 values)

typedef short  bsh8   __attribute__((ext_vector_type(8)));   // 8 bf16 (4 VGPR) MFMA frag
typedef float  f32x16 __attribute__((ext_vector_type(16)));  // 32x32 MFMA acc
typedef unsigned int u32x4 __attribute__((ext_vector_type(4)));

static __device__ __forceinline__ unsigned short f2bf(float f) {
  unsigned u = __builtin_bit_cast(unsigned, f);
  u += 0x7fffu + ((u >> 16) & 1u);      // RNE
  return (unsigned short)(u >> 16);
}

static __device__ __forceinline__ unsigned pack2(float a, float b) {
  __hip_bfloat162 h = __float22bfloat162_rn(make_float2(a, b));
  unsigned u; __builtin_memcpy(&u, &h, 4);
  return u;                              // a -> low 16, b -> high 16
}

// =====================================================================
// K1: build combined coefficients — slim-LDS (45.4KB -> 3 blocks/CU,
// all 361 blocks co-resident; R12 verified −6us).
// =====================================================================
__global__ __launch_bounds__(256, 3) void coeff_kernel(
    const int*   __restrict__ psi_idx,
    const float* __restrict__ psi_vals,
    const float* __restrict__ weight,
    unsigned short* __restrict__ Cg)
{
  __shared__ unsigned short Cl16[256 * 83];   // 42496 B
  __shared__ float S[KT][80];                 // 2880 B

  const int x = blockIdx.x, tid = threadIdx.x;

  for (int i = tid; i < KT * 80; i += 256) ((float*)S)[i] = 0.f;
  __syncthreads();

  for (int i = tid; i < KT * NNZ_; i += 256) {   // scatter all 288 taps
    int k = i >> 5, n = i & 31;
    int gi  = (k * HOUT_ + x) * NNZ_ + n;
    int idx = psi_idx[gi];
    int r   = idx / WIN;
    int col = idx - r * WIN;               // in [0,16)
    int s   = r - 2 * x + 2;               // in [0,4] after reference clip
    int slot = (s * 2 + (col & 1)) * 8 + (col >> 1);
    atomicAdd(&S[k][slot], psi_vals[gi]);
  }

  // thread (o = tid>>3, c = tid&7) reads its own 9 weights from global
  float w[KT];
  #pragma unroll
  for (int k = 0; k < KT; ++k) w[k] = weight[tid * KT + k];
  __syncthreads();

  { // dense combine, bf16 write
    unsigned short* seg = &Cl16[tid * 83];
    #pragma unroll
    for (int slot = 0; slot < 80; ++slot) {
      float acc = 0.f;
      #pragma unroll
      for (int k = 0; k < KT; ++k) acc += w[k] * S[k][slot];
      seg[slot] = f2bf(acc);
    }
  }
  __syncthreads();

  // writeback as 16B chunks: Cg[((x*8+j)*10+qb)*32+o][qi0..7]
  for (int chunk = tid; chunk < 8 * 10 * 32; chunk += 256) {
    int j   = chunk / 320;
    int rem = chunk - j * 320;
    int qb  = rem >> 5, o = rem & 31;
    u32x4 pack;
    #pragma unroll
    for (int h = 0; h < 4; ++h) {
      int q0 = qb * 8 + 2 * h;
      int c0 = q0 / 10, ql0 = q0 - c0 * 10;
      int q1 = q0 + 1;
      int c1 = q1 / 10, ql1 = q1 - c1 * 10;
      unsigned lo = Cl16[(o * CIN_ + c0) * 83 + ql0 * 8 + j];
      unsigned hi = Cl16[(o * CIN_ + c1) * 83 + ql1 * 8 + j];
      pack[h] = lo | (hi << 16);
    }
    *(u32x4*)&Cg[((size_t)x * 2560 + (size_t)((j * 10 + qb) * 32 + o)) * 8] = pack;
  }
}

// =====================================================================
// K2: main compute — R13/R15 configuration RESTORED (best measured,
// reproduced twice: 86.26 / 86.35 us graph).
// R16 lesson: plain stores leave 132MB dirty in L2/L3; lazy writeback
// collides with the NEXT graph replay's fetches (+25% end-to-end).
// Nontemporal streams the output during the MFMA tail -> keep nt.
//  - PB=256, 2 acc/wave; RST=176 no-swizzle (48 mod 128 walk -> b128
//    reads at the 8-dword/bank floor); rowpair b128 writes ~2-way.
//  - A-frag 2-slot rotation afr[j&1]; j=0/1 issued before staging.
//  - B-frag depth-1 cross-j prefetch; s_setprio(1) around MFMA cluster.
//  - LDS 264*176 = 46464B -> 3 blocks/CU.
// Plateau: occupancy-invariance (R4/R6/R7) + six refuted mutations
// (R9/R10/R11/R14/R16, fused coeff) bound this as the plain-HIP
// latency plateau, ~2.3x the 37us pure-HBM floor.
// =====================================================================
#define PB   256
#define ROWS 264            // max row read = 262
#define RST  176            // 176 mod 128 = 48 -> b128 reads at bank floor

__global__ __launch_bounds__(256, 3) void disco_main_kernel(
    const float* __restrict__ x,
    const unsigned short* __restrict__ Cg,
    float* __restrict__ out)
{
  __shared__ __align__(16) unsigned char Ut[ROWS * RST];  // 46464 B

  // ---- bijective XCD-chunked decode (nwg = 4332 = 8*541 + 4, m204) ----
  const int g   = blockIdx.x;
  const int xcd = g & 7, lin = g >> 3;
  const int swz = (xcd < 4) ? xcd * 542 + lin : 4 * 542 + (xcd - 4) * 541 + lin;
  const int xo  = swz / 12;
  const int rem = swz - xo * 12;
  const int pt  = rem % 3;          // 0..2
  const int b   = rem / 3;          // 0..3
  const int p0  = pt * PB;
  const int tid = threadIdx.x;

  const int lane = tid & 63;
  const int wv   = tid >> 6;        // 0..3: 64-wide p slice
  const int half = lane >> 5;       // k-slice half (chunk parity)
  const int l31  = lane & 31;
  const int wbase = wv * 64;

  const unsigned short* cgx = Cg + (size_t)xo * 2560 * 8
                                 + (size_t)(half * 32 + l31) * 8;

  // ---- A-frags for j=0 and j=1 issued first: overlap staging + barrier ----
  bsh8 afr[2][5];
  #pragma unroll
  for (int kb = 0; kb < 5; ++kb) afr[0][kb] = *(const bsh8*)&cgx[kb * 512];
  #pragma unroll
  for (int kb = 0; kb < 5; ++kb) afr[1][kb] = *(const bsh8*)&cgx[2560 + kb * 512];

  const float* xb = x + (size_t)b * (CIN_ * HIN * WIN);

  int rr[5];
  #pragma unroll
  for (int s = 0; s < 5; ++s) {
    int r = 2 * xo + s - 2;
    rr[s] = r < 0 ? 0 : (r > HIN - 1 ? HIN - 1 : r);
  }

  // ---- stage Ut: 1320 units (ch = u/132, rp = u%132 -> rows 2rp,2rp+1) ----
  // unit: 4 float4 loads (q-pairs 4ch+m, m=0..3) -> 2x ds_write_b128
  #pragma unroll
  for (int bp = 0; bp < 2; ++bp) {
    float4 v0[4], v1[4];
    const int uA = tid + (2 * bp) * 256, uB = uA + 256;
    const int chA = uA / 132, rpA = uA - chA * 132;
    const int chB = uB / 132, rpB = uB - chB * 132;
    int cwA = p0 + 2 * rpA; if (cwA >= WOUT_) cwA -= WOUT_;
    int cwB = p0 + 2 * rpB; if (cwB >= WOUT_) cwB -= WOUT_;
    #pragma unroll
    for (int m = 0; m < 4; ++m) {
      int qpA = 4 * chA + m, cA = (qpA * 205) >> 10, sA = qpA - cA * 5;
      v0[m] = *(const float4*)&xb[(size_t)(cA * HIN + rr[sA]) * WIN + 2 * cwA];
      int qpB = 4 * chB + m, cB = (qpB * 205) >> 10, sB = qpB - cB * 5;
      v1[m] = *(const float4*)&xb[(size_t)(cB * HIN + rr[sB]) * WIN + 2 * cwB];
    }
    u32x4 lo, hi;
    #pragma unroll
    for (int m = 0; m < 4; ++m) { lo[m] = pack2(v0[m].x, v0[m].y); hi[m] = pack2(v0[m].z, v0[m].w); }
    int byte0 = (2 * rpA) * RST + chA * 16;
    *(u32x4*)&Ut[byte0]       = lo;
    *(u32x4*)&Ut[byte0 + RST] = hi;
    #pragma unroll
    for (int m = 0; m < 4; ++m) { lo[m] = pack2(v1[m].x, v1[m].y); hi[m] = pack2(v1[m].z, v1[m].w); }
    byte0 = (2 * rpB) * RST + chB * 16;
    *(u32x4*)&Ut[byte0]       = lo;
    *(u32x4*)&Ut[byte0 + RST] = hi;
  }
  { // unit pass 5 (u in [1024,1280)) + tail (u in [1280,1320), tid < 40)
    const int uA = tid + 1024;
    const int chA = uA / 132, rpA = uA - chA * 132;
    int cwA = p0 + 2 * rpA; if (cwA >= WOUT_) cwA -= WOUT_;
    float4 v0[4], v1[4];
    int chB = 0, rpB = 0;
    const bool tail = tid < 40;
    if (tail) {
      const int uB = tid + 1280;
      chB = uB / 132; rpB = uB - chB * 132;
    }
    int cwB = p0 + 2 * rpB; if (cwB >= WOUT_) cwB -= WOUT_;
    #pragma unroll
    for (int m = 0; m < 4; ++m) {
      int qpA = 4 * chA + m, cA = (qpA * 205) >> 10, sA = qpA - cA * 5;
      v0[m] = *(const float4*)&xb[(size_t)(cA * HIN + rr[sA]) * WIN + 2 * cwA];
    }
    if (tail) {
      #pragma unroll
      for (int m = 0; m < 4; ++m) {
        int qpB = 4 * chB + m, cB = (qpB * 205) >> 10, sB = qpB - cB * 5;
        v1[m] = *(const float4*)&xb[(size_t)(cB * HIN + rr[sB]) * WIN + 2 * cwB];
      }
    }
    u32x4 lo, hi;
    #pragma unroll
    for (int m = 0; m < 4; ++m) { lo[m] = pack2(v0[m].x, v0[m].y); hi[m] = pack2(v0[m].z, v0[m].w); }
    int byte0 = (2 * rpA) * RST + chA * 16;
    *(u32x4*)&Ut[byte0]       = lo;
    *(u32x4*)&Ut[byte0 + RST] = hi;
    if (tail) {
      #pragma unroll
      for (int m = 0; m < 4; ++m) { lo[m] = pack2(v1[m].x, v1[m].y); hi[m] = pack2(v1[m].z, v1[m].w); }
      byte0 = (2 * rpB) * RST + chB * 16;
      *(u32x4*)&Ut[byte0]       = lo;
      *(u32x4*)&Ut[byte0 + RST] = hi;
    }
  }
  __syncthreads();

  // ---- MFMA phase: cross-j pipelined ----
  f32x16 acc0 = {};
  f32x16 acc1 = {};

  bsh8 bc0[5], bc1[5];                 // current-j B-frags
  {
    const int rb0 = (wbase + l31) * RST;
    const int rb1 = rb0 + 32 * RST;
    #pragma unroll
    for (int kb = 0; kb < 5; ++kb) {
      const int cho = (2 * kb + half) * 16;
      bc0[kb] = *(const bsh8*)&Ut[rb0 + cho];
      bc1[kb] = *(const bsh8*)&Ut[rb1 + cho];
    }
  }

  #pragma unroll
  for (int j = 0; j < 8; ++j) {
    bsh8 bn0[5], bn1[5];
    if (j < 7) {                       // prefetch j+1's B-frags first
      const int rb0 = (wbase + l31 + j + 1) * RST;
      const int rb1 = rb0 + 32 * RST;
      #pragma unroll
      for (int kb = 0; kb < 5; ++kb) {
        const int cho = (2 * kb + half) * 16;
        bn0[kb] = *(const bsh8*)&Ut[rb0 + cho];
        bn1[kb] = *(const bsh8*)&Ut[rb1 + cho];
      }
    }
    __builtin_amdgcn_s_setprio(1);
    #pragma unroll
    for (int kb = 0; kb < 5; ++kb) {
      acc0 = __builtin_amdgcn_mfma_f32_32x32x16_bf16(afr[j & 1][kb], bc0[kb], acc0, 0, 0, 0);
      acc1 = __builtin_amdgcn_mfma_f32_32x32x16_bf16(afr[j & 1][kb], bc1[kb], acc1, 0, 0, 0);
    }
    __builtin_amdgcn_s_setprio(0);
    if (j < 6) {                       // reload this slot with j+2's A-frags
      #pragma unroll
      for (int kb = 0; kb < 5; ++kb)
        afr[j & 1][kb] = *(const bsh8*)&cgx[(j + 2) * 2560 + kb * 512];
    }
    #pragma unroll
    for (int kb = 0; kb < 5; ++kb) { bc0[kb] = bn0[kb]; bc1[kb] = bn1[kb]; }
  }

  // ---- store: D col = l31 -> p, row o = (r&3) + 8*(r>>2) + 4*half ----
  const int p = p0 + wbase + l31;
  #pragma unroll
  for (int r = 0; r < 16; ++r) {
    int o = (r & 3) + 8 * (r >> 2) + 4 * half;
    size_t base = ((size_t)(b * COUT_ + o) * HOUT_ + xo) * WOUT_;
    if (p < WOUT_)
      __builtin_nontemporal_store(acc0[r], &out[base + p]);
    if (p + 32 < WOUT_)
      __builtin_nontemporal_store(acc1[r], &out[base + p + 32]);
  }
}

extern "C" void kernel_launch(void* const* d_in, const int* in_sizes, int n_in,
                              void* d_out, int out_size, void* d_ws, size_t ws_size,
                              hipStream_t stream) {
  const float* x        = (const float*)d_in[0];
  const int*   psi_idx  = (const int*)d_in[1];
  const float* psi_vals = (const float*)d_in[2];
  const float* weight   = (const float*)d_in[3];
  float* out = (float*)d_out;
  unsigned short* Cg = (unsigned short*)d_ws;   // 361*2560*8 bf16 = 14.8 MB

  coeff_kernel<<<dim3(HOUT_), 256, 0, stream>>>(psi_idx, psi_vals, weight, Cg);
  disco_main_kernel<<<dim3(3 * NB * HOUT_), 256, 0, stream>>>(x, Cg, out);
}